// Round 5
// baseline (638.112 us; speedup 1.0000x reference)
//
#include <hip/hip_runtime.h>
#include <cstdint>

// Problem constants
#define NN     20000      // nodes
#define NE     320000     // input edges
#define ETOT   340000     // edges + self loops
#define K1R    3000       // in_dim
#define K1     3072       // padded K for GEMM1
#define NPAD   20224      // 79*256 padded rows (256-tile GEMM1)
#define NCOL1  2048       // 4 x 512 packed outputs (xl_s|xr_s|xl_p|xr_p)
#define LDA2   1024       // layer-2 A row (hi 512 | lo 512)
#define MU_SZ  1280000    // 20000*64

typedef __bf16 bf16x8 __attribute__((ext_vector_type(8)));
typedef float f32x4 __attribute__((ext_vector_type(4)));
typedef unsigned short u16x8 __attribute__((ext_vector_type(8)));

__device__ inline unsigned short f2bf(float f) {
  union { float f; unsigned u; } v; v.f = f;
  unsigned r = v.u + 0x7FFFu + ((v.u >> 16) & 1u);
  return (unsigned short)(r >> 16);
}
__device__ inline float bf2f(unsigned short h) {
  union { unsigned u; float f; } v; v.u = ((unsigned)h) << 16;
  return v.f;
}

typedef const __attribute__((address_space(1))) void* gas1_t;
typedef __attribute__((address_space(3))) void* las3_t;
__device__ inline void llds16(const void* g, void* l) {
  __builtin_amdgcn_global_load_lds((gas1_t)(uintptr_t)g,
                                   (las3_t)(uint32_t)(uintptr_t)l, 16, 0, 0);
}

// ---------------- conversion / packing ----------------

__global__ __launch_bounds__(256)
void k_convert_x(const float* __restrict__ X, unsigned short* __restrict__ Xb) {
  const int CH = K1 / 8;                       // 384 chunks per row
  int idx = blockIdx.x * 256 + threadIdx.x;
  if (idx >= NPAD * CH) return;
  int r = idx / CH, c8 = (idx % CH) * 8;
  u16x8 o;
  if (r < NN && c8 < K1R) {                    // 3000 % 8 == 0: chunks never straddle
    const float4* p = (const float4*)(X + (size_t)r * K1R + c8);
    float4 a = p[0], b = p[1];
    o[0]=f2bf(a.x); o[1]=f2bf(a.y); o[2]=f2bf(a.z); o[3]=f2bf(a.w);
    o[4]=f2bf(b.x); o[5]=f2bf(b.y); o[6]=f2bf(b.z); o[7]=f2bf(b.w);
  } else {
#pragma unroll
    for (int j = 0; j < 8; j++) o[j] = 0;
  }
  *(u16x8*)(Xb + (size_t)r * K1 + c8) = o;
}

// Pack 4x [3000,512] f32 -> Wp[2048][3072] bf16 (B^T layout), zero-pad k>=3000.
__global__ __launch_bounds__(256)
void k_pack_w1(const float* __restrict__ W0, const float* __restrict__ W1,
               const float* __restrict__ W2, const float* __restrict__ W3,
               unsigned short* __restrict__ Wp) {
  __shared__ float tile[64][65];
  int k0 = blockIdx.x * 64, n0 = blockIdx.y * 64;
  int m = n0 >> 9, c0 = n0 & 511;
  const float* W = (m == 0) ? W0 : (m == 1) ? W1 : (m == 2) ? W2 : W3;
  int tx = threadIdx.x & 63, ty = threadIdx.x >> 6;
#pragma unroll
  for (int rep = 0; rep < 16; rep++) {
    int i = ty + rep * 4;
    int k = k0 + i;
    tile[i][tx] = (k < K1R) ? W[(size_t)k * 512 + c0 + tx] : 0.f;
  }
  __syncthreads();
#pragma unroll
  for (int rep = 0; rep < 16; rep++) {
    int i = ty + rep * 4;
    Wp[(size_t)(n0 + i) * K1 + k0 + tx] = f2bf(tile[tx][i]);
  }
}

// Pack layer-2 weights: B2[n][k], n<64 from Wl, n>=64 from Wr; k repeats 0..511 twice (hi|lo).
__global__ __launch_bounds__(256)
void k_pack_w2(const float* __restrict__ Wl, const float* __restrict__ Wr,
               unsigned short* __restrict__ B2) {
  int idx = blockIdx.x * 256 + threadIdx.x;
  if (idx >= 128 * 1024) return;
  int n = idx >> 10, k = idx & 1023, kk = k & 511;
  float v = (n < 64) ? Wl[(size_t)kk * 64 + n] : Wr[(size_t)kk * 64 + (n - 64)];
  B2[idx] = f2bf(v);
}

// ---------------- CSR build ----------------

__global__ __launch_bounds__(256)
void k_count(const int* __restrict__ ei, int* __restrict__ counts) {
  int e = blockIdx.x * 256 + threadIdx.x;
  if (e >= ETOT) return;
  int dst = (e < NE) ? ei[NE + e] : (e - NE);
  atomicAdd(&counts[dst], 1);
}

__global__ void k_scan(const int* __restrict__ counts, int* __restrict__ row_ptr) {
  __shared__ int part[1024];
  int t = threadIdx.x;
  int base = t * 20;
  int loc[20];
  int s = 0;
#pragma unroll
  for (int i = 0; i < 20; i++) {
    int idx = base + i;
    loc[i] = s;
    s += (idx < NN) ? counts[idx] : 0;
  }
  part[t] = s;
  __syncthreads();
  for (int off = 1; off < 1024; off <<= 1) {
    int v = (t >= off) ? part[t - off] : 0;
    __syncthreads();
    part[t] += v;
    __syncthreads();
  }
  int pre = (t > 0) ? part[t - 1] : 0;
#pragma unroll
  for (int i = 0; i < 20; i++) {
    int idx = base + i;
    if (idx <= NN) row_ptr[idx] = pre + loc[i];
  }
}

__global__ __launch_bounds__(256)
void k_scatter(const int* __restrict__ ei, const int* __restrict__ row_ptr,
               int* __restrict__ fill, int* __restrict__ csr_src) {
  int e = blockIdx.x * 256 + threadIdx.x;
  if (e >= ETOT) return;
  int s_, d_;
  if (e < NE) { s_ = ei[e]; d_ = ei[NE + e]; } else { s_ = d_ = e - NE; }
  int pos = row_ptr[d_] + atomicAdd(&fill[d_], 1);
  csr_src[pos] = s_;
}

// ---------------- GEMM1: 256x256, 4 pinned phases per K-tile ----------------
// C[20224,2048] bf16 = A[20224,3072] * B^T[2048,3072], both bf16, lda=ldb=3072.
// LDS 128KiB: A halves at (buf*2+mh)*16384, B halves at 65536+(buf*2+nh)*16384.
// Per phase: {reads, stage issue, [counted vmcnt], s_barrier, lgkmcnt(0),
// sched_barrier(0) [rule #18: pin MFMA after the wait], setprio, 16 MFMA}.
// Waves cross each barrier after ISSUING reads; per-wave lgkmcnt staggers MFMA
// starts in LDS-queue order so read-drain overlaps neighboring MFMA clusters.
// Stage stream per K-tile t (for t+1): P1 issues A0',B0'; P2 issues B1',A1'.
// Cross-wave visibility: vmcnt(4) in P1 (A1' landed) publishes via P1 barrier of
// t+1 before P2's a1-reads; vmcnt(2) at boundary (A0',B0',B1' landed) publishes
// via boundary barrier. LDS overwrite hazards all carry >=1 barrier.

#define NT1 48

#define STAGE_ONE do { \
  if (sctr < 4 * NT1) { \
    int ts_ = sctr >> 2, o_ = sctr & 3, sb_ = ts_ & 1; \
    const unsigned short* gb_; char* lb_; int rb_; \
    if (o_ == 0)      { gb_ = A; rb_ = bmBase;       lb_ = lds + (sb_*2+0)*16384; } \
    else if (o_ == 1) { gb_ = B; rb_ = bnBase;       lb_ = lds + 65536 + (sb_*2+0)*16384; } \
    else if (o_ == 2) { gb_ = B; rb_ = bnBase + 128; lb_ = lds + 65536 + (sb_*2+1)*16384; } \
    else              { gb_ = A; rb_ = bmBase + 128; lb_ = lds + (sb_*2+1)*16384; } \
    const unsigned short* g0_ = gb_ + (size_t)(rb_ + trow) * 3072 + ts_ * 64 + scol; \
    llds16(g0_, lb_ + wid * 1024); \
    llds16(g0_ + (size_t)64 * 3072, lb_ + 8192 + wid * 1024); \
    sctr++; \
  } \
} while (0)

#define RDA(DST, BASE) do { \
  _Pragma("unroll") \
  for (int mi = 0; mi < 2; mi++) { \
    int r_ = rw * 32 + mi * 16 + l15; \
    DST[0][mi] = *(const bf16x8*)((BASE) + r_ * 128 + sw0); \
    DST[1][mi] = *(const bf16x8*)((BASE) + r_ * 128 + sw1); \
  } \
} while (0)

#define RDB(DST, BASE) do { \
  _Pragma("unroll") \
  for (int ni = 0; ni < 4; ni++) { \
    int r_ = cw * 64 + ni * 16 + l15; \
    DST[0][ni] = *(const bf16x8*)((BASE) + r_ * 128 + sw0); \
    DST[1][ni] = *(const bf16x8*)((BASE) + r_ * 128 + sw1); \
  } \
} while (0)

#define MF(MH, NH, AV, BV) do { \
  _Pragma("unroll") \
  for (int mi = 0; mi < 2; mi++) \
    _Pragma("unroll") \
    for (int ni = 0; ni < 4; ni++) { \
      acc[MH][NH][mi][ni] = __builtin_amdgcn_mfma_f32_16x16x32_bf16(AV[0][mi], BV[0][ni], acc[MH][NH][mi][ni], 0, 0, 0); \
      acc[MH][NH][mi][ni] = __builtin_amdgcn_mfma_f32_16x16x32_bf16(AV[1][mi], BV[1][ni], acc[MH][NH][mi][ni], 0, 0, 0); \
    } \
} while (0)

// barrier + per-wave LDS drain + scheduler pin (rule #18), then MFMA cluster
#define PH_ENTER do { \
  asm volatile("" ::: "memory"); \
  __builtin_amdgcn_s_barrier(); \
  asm volatile("s_waitcnt lgkmcnt(0)" ::: "memory"); \
  __builtin_amdgcn_sched_barrier(0); \
  __builtin_amdgcn_s_setprio(1); \
} while (0)

#define PH_EXIT do { \
  __builtin_amdgcn_s_setprio(0); \
  __builtin_amdgcn_sched_barrier(0); \
} while (0)

__global__ __launch_bounds__(512, 2)
void gemm256(const unsigned short* __restrict__ A, const unsigned short* __restrict__ B,
             unsigned short* __restrict__ C) {
  __shared__ char lds[131072];
  int tid = threadIdx.x, wid = tid >> 6, lane = tid & 63;
  int l15 = lane & 15;
  int rw = wid & 3, cw = wid >> 2;               // 4 row-blocks x 2 col-blocks per quadrant
  int bid = blockIdx.x;
  int swz = (bid & 7) * 79 + (bid >> 3);         // XCD swizzle: 632 = 8*79 exactly
  int bm = swz % 79, bn = swz / 79;              // bm-major within bn -> B panel L2-resident
  int bmBase = bm * 256, bnBase = bn * 256;
  int trow = tid >> 3;                           // staging row within 64-row issue
  int scol = ((tid & 7) ^ ((tid >> 3) & 7)) * 8; // pre-swizzled global k-offset (elems)
  int sw0 = (((lane >> 4) + 0) ^ (lane & 7)) * 16;  // read-side swizzled byte col, kk=0
  int sw1 = (((lane >> 4) + 4) ^ (lane & 7)) * 16;  // kk=1
  f32x4 acc[2][2][2][4] = {};

  int sctr = 0;
  // prologue: stage tile 0 fully, then wait for it
  for (int i = 0; i < 4; i++) STAGE_ONE;
  asm volatile("s_waitcnt vmcnt(0)" ::: "memory");
  __builtin_amdgcn_s_barrier();
  asm volatile("" ::: "memory");

  for (int t = 0; t < NT1; t++) {
    int buf = t & 1;
    const char* A0h = lds + (buf * 2 + 0) * 16384;
    const char* A1h = lds + (buf * 2 + 1) * 16384;
    const char* B0h = lds + 65536 + (buf * 2 + 0) * 16384;
    const char* B1h = lds + 65536 + (buf * 2 + 1) * 16384;
    bf16x8 a0[2][2], a1[2][2], b0[2][4], b1[2][4];

    // P1: quadrant (0,0) — reads a0,b0; stage A0',B0'; vmcnt(4) -> A1' landed
    RDA(a0, A0h);
    RDB(b0, B0h);
    STAGE_ONE; STAGE_ONE;
    asm volatile("s_waitcnt vmcnt(4)" ::: "memory");
    PH_ENTER;
    MF(0, 0, a0, b0);
    PH_EXIT;

    // P2: quadrant (1,0) — reads a1 (b0 in regs); stage B1',A1'
    RDA(a1, A1h);
    STAGE_ONE; STAGE_ONE;
    PH_ENTER;
    MF(1, 0, a1, b0);
    PH_EXIT;

    // P3: quadrant (1,1) — reads b1 (a1 in regs)
    RDB(b1, B1h);
    PH_ENTER;
    MF(1, 1, a1, b1);
    PH_EXIT;

    // P4: quadrant (0,1) — pure register phase; boundary: vmcnt(2) -> A0',B0',B1'
    __builtin_amdgcn_s_setprio(1);
    MF(0, 1, a0, b1);
    __builtin_amdgcn_s_setprio(0);
    __builtin_amdgcn_sched_barrier(0);
    asm volatile("s_waitcnt vmcnt(2)" ::: "memory");
    __builtin_amdgcn_s_barrier();
    asm volatile("" ::: "memory");
  }

  // epilogue: repack each 128x128 quadrant via LDS, store bf16x8 rows
  unsigned short (*sq)[128] = (unsigned short (*)[128])lds;
#pragma unroll
  for (int mh = 0; mh < 2; mh++)
#pragma unroll
    for (int nh = 0; nh < 2; nh++) {
      __syncthreads();
#pragma unroll
      for (int mi = 0; mi < 2; mi++)
#pragma unroll
        for (int ni = 0; ni < 4; ni++)
#pragma unroll
          for (int r = 0; r < 4; r++)
            sq[rw * 32 + mi * 16 + (lane >> 4) * 4 + r][cw * 64 + ni * 16 + l15] =
                f2bf(acc[mh][nh][mi][ni][r]);
      __syncthreads();
#pragma unroll
      for (int it = 0; it < 4; it++) {
        int idx = it * 512 + tid;
        int row = idx >> 4, ch = idx & 15;
        *(u16x8*)(C + (size_t)(bmBase + mh * 128 + row) * NCOL1 + bnBase + nh * 128 + ch * 8) =
            *(const u16x8*)&sq[row][ch * 8];
      }
    }
}

// ---------------- layer-2 GEMM (128-tile m97 structure), both branches in one grid ----------------
// grid (157, 2): y=0 -> s-branch, y=1 -> p-branch. C[n,0:64]=xl2, [64:128]=xr2 (fp32).

__global__ __launch_bounds__(256)
void gemm_l2(const unsigned short* __restrict__ As, const unsigned short* __restrict__ Bs,
             float* __restrict__ Cs,
             const unsigned short* __restrict__ Ap, const unsigned short* __restrict__ Bp,
             float* __restrict__ Cp) {
  const int K = LDA2, lda = LDA2, ldb = LDA2, ldc = 128, mreal = NN;
  const unsigned short* A = blockIdx.y ? Ap : As;
  const unsigned short* B = blockIdx.y ? Bp : Bs;
  float* C = blockIdx.y ? Cp : Cs;
  __shared__ char smem_raw[16384];
  unsigned short* sA = (unsigned short*)smem_raw;
  unsigned short* sB = sA + 128 * 32;
  int bm = blockIdx.x;
  int tid = threadIdx.x, wid = tid >> 6, lane = tid & 63;
  int wr = wid >> 1, wc = wid & 1;
  f32x4 acc[4][4] = {};

  int ar = 32 * wid + (lane >> 2);
  int acol = (lane & 3) * 8;
  const unsigned short* Ag = A + (size_t)(bm * 128 + ar) * lda + acol;
  const unsigned short* Bg = B + (size_t)ar * ldb + acol;
  unsigned short* la0 = sA + (wid * 2) * 512;
  unsigned short* lb0 = sB + (wid * 2) * 512;
  int frow = lane & 15, koff = (lane >> 4) * 8;

  for (int kt = 0; kt < K; kt += 32) {
    llds16(Ag + kt, la0);
    llds16(Ag + kt + (size_t)16 * lda, la0 + 512);
    llds16(Bg + kt, lb0);
    llds16(Bg + kt + (size_t)16 * ldb, lb0 + 512);
    __syncthreads();
    bf16x8 af[4], bfr[4];
#pragma unroll
    for (int mi = 0; mi < 4; mi++)
      af[mi] = *(const bf16x8*)(sA + (wr * 64 + mi * 16 + frow) * 32 + koff);
#pragma unroll
    for (int ni = 0; ni < 4; ni++)
      bfr[ni] = *(const bf16x8*)(sB + (wc * 64 + ni * 16 + frow) * 32 + koff);
#pragma unroll
    for (int mi = 0; mi < 4; mi++)
#pragma unroll
      for (int ni = 0; ni < 4; ni++)
        acc[mi][ni] = __builtin_amdgcn_mfma_f32_16x16x32_bf16(af[mi], bfr[ni], acc[mi][ni], 0, 0, 0);
    __syncthreads();
  }

#pragma unroll
  for (int mi = 0; mi < 4; mi++) {
    int grow0 = bm * 128 + wr * 64 + mi * 16 + (lane >> 4) * 4;
#pragma unroll
    for (int ni = 0; ni < 4; ni++) {
      int gcol = wc * 64 + ni * 16 + (lane & 15);
#pragma unroll
      for (int r = 0; r < 4; r++) {
        int grow = grow0 + r;
        if (grow < mreal) C[(size_t)grow * ldc + gcol] = acc[mi][ni][r];
      }
    }
  }
}

// ---------------- layer-1 fused edge softmax + aggregate + activation + hi/lo split ----------------

__global__ __launch_bounds__(256)
void edge_agg1(const unsigned short* __restrict__ XL1,
               const int* __restrict__ row_ptr, const int* __restrict__ csr_src,
               const float* __restrict__ att_s, const float* __restrict__ att_p,
               const float* __restrict__ b_s, const float* __restrict__ b_p,
               unsigned short* __restrict__ A2s, unsigned short* __restrict__ A2p) {
  int gw = (blockIdx.x * 256 + threadIdx.x) >> 6;
  if (gw >= NN * 2) return;
  int n = gw >> 1, br = gw & 1;
  int lane = threadIdx.x & 63;
  int cb = lane * 8;
  const float* att = br ? att_p : att_s;
  const float* bias = br ? b_p : b_s;
  float xr[8], at[8], agg[8];
  bf16x8 xrv = *(const bf16x8*)(XL1 + (size_t)n * NCOL1 + br * 1024 + 512 + cb);
#pragma unroll
  for (int j = 0; j < 8; j++) { xr[j] = (float)xrv[j]; at[j] = att[cb + j]; agg[j] = 0.f; }
  float M = -1e30f, S = 0.f;
  const size_t srcoff = (size_t)br * 1024 + cb;
  int pe = row_ptr[n + 1];
  for (int p = row_ptr[n]; p < pe; ++p) {
    int src = csr_src[p];
    bf16x8 mv = *(const bf16x8*)(XL1 + (size_t)src * NCOL1 + srcoff);
    float mj[8], part = 0.f;
#pragma unroll
    for (int j = 0; j < 8; j++) {
      mj[j] = (float)mv[j];
      float t = mj[j] + xr[j];
      t = (t > 0.f) ? t : 0.2f * t;
      part = fmaf(at[j], t, part);
    }
#pragma unroll
    for (int w = 1; w < 16; w <<= 1) part += __shfl_xor(part, w);
    float nm = fmaxf(M, part);
    float fac = __expf(M - nm);
    float wgt = __expf(part - nm);
    S = S * fac + wgt;
#pragma unroll
    for (int j = 0; j < 8; j++) agg[j] = agg[j] * fac + wgt * mj[j];
    M = nm;
  }
  float inv = 1.f / S;
  u16x8 hv, lv;
  unsigned short* A2 = br ? A2p : A2s;
#pragma unroll
  for (int j = 0; j < 8; j++) {
    float v = agg[j] * inv + bias[cb + j];
    if (!br) v = fmaxf(v, 0.f);
    unsigned short h = f2bf(v);
    float lo = v - bf2f(h);
    hv[j] = h; lv[j] = f2bf(lo);
  }
  *(u16x8*)(A2 + (size_t)n * LDA2 + cb) = hv;
  *(u16x8*)(A2 + (size_t)n * LDA2 + 512 + cb) = lv;
}

// ---------------- layer-2 fused edge softmax + aggregate + final epilogue ----------------

__global__ __launch_bounds__(256)
void edge_agg2(const float* __restrict__ C2s, const float* __restrict__ C2p,
               const int* __restrict__ row_ptr, const int* __restrict__ csr_src,
               const float* __restrict__ att_s, const float* __restrict__ att_p,
               const float* __restrict__ b_s, const float* __restrict__ b_p,
               float* __restrict__ out) {
  int gw = (blockIdx.x * 256 + threadIdx.x) >> 6;
  if (gw >= NN * 2) return;
  int n = gw >> 1, br = gw & 1;
  int lane = threadIdx.x & 63;
  const float* C2 = br ? C2p : C2s;
  float xr = C2[(size_t)n * 128 + 64 + lane];
  float at = (br ? att_p : att_s)[lane];
  float M = -1e30f, S = 0.f, agg = 0.f;
  int pe = row_ptr[n + 1];
  for (int p = row_ptr[n]; p < pe; ++p) {
    int src = csr_src[p];
    float m = C2[(size_t)src * 128 + lane];
    float t = m + xr;
    t = (t > 0.f) ? t : 0.2f * t;
    float part = at * t;
#pragma unroll
    for (int w = 1; w < 64; w <<= 1) part += __shfl_xor(part, w);
    float nm = fmaxf(M, part);
    float fac = __expf(M - nm);
    float wgt = __expf(part - nm);
    S = S * fac + wgt;
    agg = agg * fac + wgt * m;
    M = nm;
  }
  float v = agg / S + (br ? b_p : b_s)[lane];
  if (lane < 32) {
    out[(size_t)n * 64 + br * 32 + lane] = v;
  } else {
    float sp = fmaxf(v, 0.f) + log1pf(__expf(-fabsf(v))) + 1e-6f;
    out[(size_t)MU_SZ + n * 64 + br * 32 + (lane - 32)] = sp;
  }
}

// ---------------- host ----------------

extern "C" void kernel_launch(void* const* d_in, const int* in_sizes, int n_in,
                              void* d_out, int out_size, void* d_ws, size_t ws_size,
                              hipStream_t stream) {
  const float* x      = (const float*)d_in[0];
  const int*   ei     = (const int*)d_in[1];
  const float* Wl_s1  = (const float*)d_in[2];
  const float* Wr_s1  = (const float*)d_in[3];
  const float* att_s1 = (const float*)d_in[4];
  const float* b_s1   = (const float*)d_in[5];
  const float* Wl_s2  = (const float*)d_in[6];
  const float* Wr_s2  = (const float*)d_in[7];
  const float* att_s2 = (const float*)d_in[8];
  const float* b_s2   = (const float*)d_in[9];
  const float* Wl_p1  = (const float*)d_in[10];
  const float* Wr_p1  = (const float*)d_in[11];
  const float* att_p1 = (const float*)d_in[12];
  const float* b_p1   = (const float*)d_in[13];
  const float* Wl_p2  = (const float*)d_in[14];
  const float* Wr_p2  = (const float*)d_in[15];
  const float* att_p2 = (const float*)d_in[16];
  const float* b_p2   = (const float*)d_in[17];

  char* ws = (char*)d_ws;
  // Region R0 [0, 124.3MB): Xb during GEMM1; reused afterwards for layer-2 buffers.
  unsigned short* Xb   = (unsigned short*)(ws + 0);           // 20224*3072*2 = 124,256,256
  unsigned short* A2s  = (unsigned short*)(ws + 0);           // 41,156,608
  unsigned short* A2p  = (unsigned short*)(ws + 41156608);    // 41,156,608
  float*          C2s  = (float*)(ws + 82313216);             // 10,240,000
  float*          C2p  = (float*)(ws + 92553216);             // 10,240,000
  unsigned short* B2s  = (unsigned short*)(ws + 102793216);   // 262,144
  unsigned short* B2p  = (unsigned short*)(ws + 103055360);   // 262,144
  unsigned short* Wp   = (unsigned short*)(ws + 124256256);   // 12,582,912
  unsigned short* XL1  = (unsigned short*)(ws + 136839168);   // 20224*2048*2 = 82,837,504
  int* counts  = (int*)(ws + 219676672);
  int* fill    = (int*)(ws + 219756672);
  int* row_ptr = (int*)(ws + 219836672);
  int* csr_src = (int*)(ws + 219916688);                      // ends ~221.3 MB

  hipMemsetAsync(counts, 0, NN * sizeof(int), stream);
  hipMemsetAsync(fill, 0, NN * sizeof(int), stream);

  k_convert_x<<<30336, 256, 0, stream>>>(x, Xb);
  k_pack_w1<<<dim3(48, 32), 256, 0, stream>>>(Wl_s1, Wr_s1, Wl_p1, Wr_p1, Wp);
  k_count<<<(ETOT + 255) / 256, 256, 0, stream>>>(ei, counts);
  k_scan<<<1, 1024, 0, stream>>>(counts, row_ptr);
  k_scatter<<<(ETOT + 255) / 256, 256, 0, stream>>>(ei, row_ptr, fill, csr_src);

  // XL1[n, 0:512|512:1024|1024:1536|1536:2048] = x@{Wl_s1|Wr_s1|Wl_p1|Wr_p1}, bf16
  gemm256<<<632, 512, 0, stream>>>(Xb, Wp, XL1);

  k_pack_w2<<<512, 256, 0, stream>>>(Wl_s2, Wr_s2, B2s);
  k_pack_w2<<<512, 256, 0, stream>>>(Wl_p2, Wr_p2, B2p);

  edge_agg1<<<10000, 256, 0, stream>>>(XL1, row_ptr, csr_src, att_s1, att_p1, b_s1, b_p1, A2s, A2p);

  // layer-2: both branches, one launch
  gemm_l2<<<dim3(157, 2), 256, 0, stream>>>(A2s, B2s, C2s, A2p, B2p, C2p);

  edge_agg2<<<10000, 256, 0, stream>>>(C2s, C2p, row_ptr, csr_src, att_s2, att_p2, b_s2, b_p2, (float*)d_out);
}

// Round 6
// 627.677 us; speedup vs baseline: 1.0166x; 1.0166x over previous
//
#include <hip/hip_runtime.h>
#include <cstdint>

// Problem constants
#define NN     20000      // nodes
#define NE     320000     // input edges
#define ETOT   340000     // edges + self loops
#define K1R    3000       // in_dim
#define K1     3072       // padded K for GEMM1
#define NPAD   20224      // 79*256 padded rows (256-tile GEMM1)
#define NCOL1  2048       // 4 x 512 packed outputs (xl_s|xr_s|xl_p|xr_p)
#define LDA2   1024       // layer-2 A row (hi 512 | lo 512)
#define MU_SZ  1280000    // 20000*64

typedef __bf16 bf16x8 __attribute__((ext_vector_type(8)));
typedef float f32x4 __attribute__((ext_vector_type(4)));
typedef unsigned short u16x8 __attribute__((ext_vector_type(8)));

__device__ inline unsigned short f2bf(float f) {
  union { float f; unsigned u; } v; v.f = f;
  unsigned r = v.u + 0x7FFFu + ((v.u >> 16) & 1u);
  return (unsigned short)(r >> 16);
}
__device__ inline float bf2f(unsigned short h) {
  union { unsigned u; float f; } v; v.u = ((unsigned)h) << 16;
  return v.f;
}

typedef const __attribute__((address_space(1))) void* gas1_t;
typedef __attribute__((address_space(3))) void* las3_t;
__device__ inline void llds16(const void* g, void* l) {
  __builtin_amdgcn_global_load_lds((gas1_t)(uintptr_t)g,
                                   (las3_t)(uint32_t)(uintptr_t)l, 16, 0, 0);
}

// ---------------- conversion / packing ----------------

__global__ __launch_bounds__(256)
void k_convert_x(const float* __restrict__ X, unsigned short* __restrict__ Xb) {
  const int CH = K1 / 8;                       // 384 chunks per row
  int idx = blockIdx.x * 256 + threadIdx.x;
  if (idx >= NPAD * CH) return;
  int r = idx / CH, c8 = (idx % CH) * 8;
  u16x8 o;
  if (r < NN && c8 < K1R) {                    // 3000 % 8 == 0: chunks never straddle
    const float4* p = (const float4*)(X + (size_t)r * K1R + c8);
    float4 a = p[0], b = p[1];
    o[0]=f2bf(a.x); o[1]=f2bf(a.y); o[2]=f2bf(a.z); o[3]=f2bf(a.w);
    o[4]=f2bf(b.x); o[5]=f2bf(b.y); o[6]=f2bf(b.z); o[7]=f2bf(b.w);
  } else {
#pragma unroll
    for (int j = 0; j < 8; j++) o[j] = 0;
  }
  *(u16x8*)(Xb + (size_t)r * K1 + c8) = o;
}

// Pack 4x [3000,512] f32 -> Wp[2048][3072] bf16 (B^T layout), zero-pad k>=3000.
__global__ __launch_bounds__(256)
void k_pack_w1(const float* __restrict__ W0, const float* __restrict__ W1,
               const float* __restrict__ W2, const float* __restrict__ W3,
               unsigned short* __restrict__ Wp) {
  __shared__ float tile[64][65];
  int k0 = blockIdx.x * 64, n0 = blockIdx.y * 64;
  int m = n0 >> 9, c0 = n0 & 511;
  const float* W = (m == 0) ? W0 : (m == 1) ? W1 : (m == 2) ? W2 : W3;
  int tx = threadIdx.x & 63, ty = threadIdx.x >> 6;
#pragma unroll
  for (int rep = 0; rep < 16; rep++) {
    int i = ty + rep * 4;
    int k = k0 + i;
    tile[i][tx] = (k < K1R) ? W[(size_t)k * 512 + c0 + tx] : 0.f;
  }
  __syncthreads();
#pragma unroll
  for (int rep = 0; rep < 16; rep++) {
    int i = ty + rep * 4;
    Wp[(size_t)(n0 + i) * K1 + k0 + tx] = f2bf(tile[tx][i]);
  }
}

// Pack layer-2 weights: B2[n][k], n<64 from Wl, n>=64 from Wr; k repeats 0..511 twice (hi|lo).
__global__ __launch_bounds__(256)
void k_pack_w2(const float* __restrict__ Wl, const float* __restrict__ Wr,
               unsigned short* __restrict__ B2) {
  int idx = blockIdx.x * 256 + threadIdx.x;
  if (idx >= 128 * 1024) return;
  int n = idx >> 10, k = idx & 1023, kk = k & 511;
  float v = (n < 64) ? Wl[(size_t)kk * 64 + n] : Wr[(size_t)kk * 64 + (n - 64)];
  B2[idx] = f2bf(v);
}

// ---------------- CSR build ----------------

__global__ __launch_bounds__(256)
void k_count(const int* __restrict__ ei, int* __restrict__ counts) {
  int e = blockIdx.x * 256 + threadIdx.x;
  if (e >= ETOT) return;
  int dst = (e < NE) ? ei[NE + e] : (e - NE);
  atomicAdd(&counts[dst], 1);
}

__global__ void k_scan(const int* __restrict__ counts, int* __restrict__ row_ptr) {
  __shared__ int part[1024];
  int t = threadIdx.x;
  int base = t * 20;
  int loc[20];
  int s = 0;
#pragma unroll
  for (int i = 0; i < 20; i++) {
    int idx = base + i;
    loc[i] = s;
    s += (idx < NN) ? counts[idx] : 0;
  }
  part[t] = s;
  __syncthreads();
  for (int off = 1; off < 1024; off <<= 1) {
    int v = (t >= off) ? part[t - off] : 0;
    __syncthreads();
    part[t] += v;
    __syncthreads();
  }
  int pre = (t > 0) ? part[t - 1] : 0;
#pragma unroll
  for (int i = 0; i < 20; i++) {
    int idx = base + i;
    if (idx <= NN) row_ptr[idx] = pre + loc[i];
  }
}

__global__ __launch_bounds__(256)
void k_scatter(const int* __restrict__ ei, const int* __restrict__ row_ptr,
               int* __restrict__ fill, int* __restrict__ csr_src) {
  int e = blockIdx.x * 256 + threadIdx.x;
  if (e >= ETOT) return;
  int s_, d_;
  if (e < NE) { s_ = ei[e]; d_ = ei[NE + e]; } else { s_ = d_ = e - NE; }
  int pos = row_ptr[d_] + atomicAdd(&fill[d_], 1);
  csr_src[pos] = s_;
}

// ---------------- GEMM1: 256x256, role-staggered waves, 1 barrier per K-tile ----------------
// C[20224,2048] bf16 = A[20224,3072] * B^T[2048,3072], both bf16, lda=ldb=3072.
// LDS 128KiB: A halves at (buf*2+mh)*16384, B halves at 65536+(buf*2+nh)*16384.
// Wave role r=(wid>>2)&1 pairs anti-phased roles on each SIMD: role 0 quadrant
// order MF00,MF10,MF11,MF01; role 1 order MF11,MF01,MF00,MF10 (operands read
// just-in-time). At any instant ~half the waves issue ds_reads while the other
// half run MFMA -> LDS and MFMA pipes both stay fed without per-phase barriers.
// Stage units for tile t+1 issued at the 4 phase tops (order A1',B1',B0',A0');
// all target buf^1, all reads target buf -> only hazard fence needed is the
// boundary vmcnt(0)+s_barrier (publishes every wave's 8 llds16 cross-wave, and
// frees buf^1 whose last reads were before the previous boundary).
// XCD mapping: bn = bid&7 == XCD (B panel 1.5MB L2-resident per XCD); bm=bid>>3
// -> all 8 columns process the same bm concurrently: A fetched from HBM once,
// L3-served to the other 7 XCDs.

#define NT1 48

#define STAGE_ONE do { \
  if (sctr < 4 * NT1) { \
    int ts_ = sctr >> 2, u_ = sctr & 3, sb_ = ts_ & 1; \
    const unsigned short* gb_; char* lb_; int rb_; \
    if (u_ == 0)      { gb_ = A; rb_ = bmBase + 128; lb_ = lds + (sb_*2+1)*16384; } \
    else if (u_ == 1) { gb_ = B; rb_ = bnBase + 128; lb_ = lds + 65536 + (sb_*2+1)*16384; } \
    else if (u_ == 2) { gb_ = B; rb_ = bnBase;       lb_ = lds + 65536 + (sb_*2+0)*16384; } \
    else              { gb_ = A; rb_ = bmBase;       lb_ = lds + (sb_*2+0)*16384; } \
    const unsigned short* g0_ = gb_ + (size_t)(rb_ + trow) * 3072 + ts_ * 64 + scol; \
    llds16(g0_, lb_ + wid * 1024); \
    llds16(g0_ + (size_t)64 * 3072, lb_ + 8192 + wid * 1024); \
    sctr++; \
  } \
} while (0)

#define RDA(DST, BASE) do { \
  _Pragma("unroll") \
  for (int mi = 0; mi < 2; mi++) { \
    int r_ = rw * 32 + mi * 16 + l15; \
    DST[0][mi] = *(const bf16x8*)((BASE) + r_ * 128 + sw0); \
    DST[1][mi] = *(const bf16x8*)((BASE) + r_ * 128 + sw1); \
  } \
} while (0)

#define RDB(DST, BASE) do { \
  _Pragma("unroll") \
  for (int ni = 0; ni < 4; ni++) { \
    int r_ = cw * 64 + ni * 16 + l15; \
    DST[0][ni] = *(const bf16x8*)((BASE) + r_ * 128 + sw0); \
    DST[1][ni] = *(const bf16x8*)((BASE) + r_ * 128 + sw1); \
  } \
} while (0)

#define MF(MH, NH, AV, BV) do { \
  __builtin_amdgcn_s_setprio(1); \
  _Pragma("unroll") \
  for (int mi = 0; mi < 2; mi++) \
    _Pragma("unroll") \
    for (int ni = 0; ni < 4; ni++) { \
      acc[MH][NH][mi][ni] = __builtin_amdgcn_mfma_f32_16x16x32_bf16(AV[0][mi], BV[0][ni], acc[MH][NH][mi][ni], 0, 0, 0); \
      acc[MH][NH][mi][ni] = __builtin_amdgcn_mfma_f32_16x16x32_bf16(AV[1][mi], BV[1][ni], acc[MH][NH][mi][ni], 0, 0, 0); \
    } \
  __builtin_amdgcn_s_setprio(0); \
} while (0)

__global__ __launch_bounds__(512, 2)
void gemm256(const unsigned short* __restrict__ A, const unsigned short* __restrict__ B,
             unsigned short* __restrict__ C) {
  __shared__ char lds[131072];
  int tid = threadIdx.x, wid = tid >> 6, lane = tid & 63;
  int l15 = lane & 15;
  int rw = wid & 3, cw = wid >> 2;               // 4 row-blocks x 2 col-blocks per quadrant
  int role = (wid >> 2) & 1;                     // SIMD-paired waves get opposite roles
  int bid = blockIdx.x;
  int bn = bid & 7, bm = bid >> 3;               // bn == XCD; same bm concurrent across XCDs
  int bmBase = bm * 256, bnBase = bn * 256;
  int trow = tid >> 3;                           // staging row within 64-row issue
  int scol = ((tid & 7) ^ ((tid >> 3) & 7)) * 8; // pre-swizzled global k-offset (elems)
  int sw0 = (((lane >> 4) + 0) ^ (lane & 7)) * 16;  // read-side swizzled byte col, kk=0
  int sw1 = (((lane >> 4) + 4) ^ (lane & 7)) * 16;  // kk=1
  f32x4 acc[2][2][2][4] = {};

  int sctr = 0;
  // prologue: stage tile 0 fully, then wait for it
  for (int i = 0; i < 4; i++) STAGE_ONE;
  asm volatile("s_waitcnt vmcnt(0)" ::: "memory");
  __builtin_amdgcn_s_barrier();
  asm volatile("" ::: "memory");

  for (int t = 0; t < NT1; t++) {
    int buf = t & 1;
    const char* A0h = lds + (buf * 2 + 0) * 16384;
    const char* A1h = lds + (buf * 2 + 1) * 16384;
    const char* B0h = lds + 65536 + (buf * 2 + 0) * 16384;
    const char* B1h = lds + 65536 + (buf * 2 + 1) * 16384;
    bf16x8 a0[2][2], a1[2][2], b0[2][4], b1[2][4];

    if (role == 0) {
      STAGE_ONE;
      RDA(a0, A0h); RDB(b0, B0h);
      MF(0, 0, a0, b0);
      STAGE_ONE;
      RDA(a1, A1h);
      MF(1, 0, a1, b0);
      STAGE_ONE;
      RDB(b1, B1h);
      MF(1, 1, a1, b1);
      STAGE_ONE;
      MF(0, 1, a0, b1);
    } else {
      STAGE_ONE;
      RDA(a1, A1h); RDB(b1, B1h);
      MF(1, 1, a1, b1);
      STAGE_ONE;
      RDA(a0, A0h);
      MF(0, 1, a0, b1);
      STAGE_ONE;
      RDB(b0, B0h);
      MF(0, 0, a0, b0);
      STAGE_ONE;
      MF(1, 0, a1, b0);
    }
    asm volatile("s_waitcnt vmcnt(0)" ::: "memory");
    __builtin_amdgcn_s_barrier();
    asm volatile("" ::: "memory");
  }

  // epilogue: repack each 128x128 quadrant via LDS, store bf16x8 rows
  unsigned short (*sq)[128] = (unsigned short (*)[128])lds;
#pragma unroll
  for (int mh = 0; mh < 2; mh++)
#pragma unroll
    for (int nh = 0; nh < 2; nh++) {
      __syncthreads();
#pragma unroll
      for (int mi = 0; mi < 2; mi++)
#pragma unroll
        for (int ni = 0; ni < 4; ni++)
#pragma unroll
          for (int r = 0; r < 4; r++)
            sq[rw * 32 + mi * 16 + (lane >> 4) * 4 + r][cw * 64 + ni * 16 + l15] =
                f2bf(acc[mh][nh][mi][ni][r]);
      __syncthreads();
#pragma unroll
      for (int it = 0; it < 4; it++) {
        int idx = it * 512 + tid;
        int row = idx >> 4, ch = idx & 15;
        *(u16x8*)(C + (size_t)(bmBase + mh * 128 + row) * NCOL1 + bnBase + nh * 128 + ch * 8) =
            *(const u16x8*)&sq[row][ch * 8];
      }
    }
}

// ---------------- layer-2 GEMM (128-tile m97 structure), both branches in one grid ----------------
// grid (157, 2): y=0 -> s-branch, y=1 -> p-branch. C[n,0:64]=xl2, [64:128]=xr2 (fp32).

__global__ __launch_bounds__(256)
void gemm_l2(const unsigned short* __restrict__ As, const unsigned short* __restrict__ Bs,
             float* __restrict__ Cs,
             const unsigned short* __restrict__ Ap, const unsigned short* __restrict__ Bp,
             float* __restrict__ Cp) {
  const int K = LDA2, lda = LDA2, ldb = LDA2, ldc = 128, mreal = NN;
  const unsigned short* A = blockIdx.y ? Ap : As;
  const unsigned short* B = blockIdx.y ? Bp : Bs;
  float* C = blockIdx.y ? Cp : Cs;
  __shared__ char smem_raw[16384];
  unsigned short* sA = (unsigned short*)smem_raw;
  unsigned short* sB = sA + 128 * 32;
  int bm = blockIdx.x;
  int tid = threadIdx.x, wid = tid >> 6, lane = tid & 63;
  int wr = wid >> 1, wc = wid & 1;
  f32x4 acc[4][4] = {};

  int ar = 32 * wid + (lane >> 2);
  int acol = (lane & 3) * 8;
  const unsigned short* Ag = A + (size_t)(bm * 128 + ar) * lda + acol;
  const unsigned short* Bg = B + (size_t)ar * ldb + acol;
  unsigned short* la0 = sA + (wid * 2) * 512;
  unsigned short* lb0 = sB + (wid * 2) * 512;
  int frow = lane & 15, koff = (lane >> 4) * 8;

  for (int kt = 0; kt < K; kt += 32) {
    llds16(Ag + kt, la0);
    llds16(Ag + kt + (size_t)16 * lda, la0 + 512);
    llds16(Bg + kt, lb0);
    llds16(Bg + kt + (size_t)16 * ldb, lb0 + 512);
    __syncthreads();
    bf16x8 af[4], bfr[4];
#pragma unroll
    for (int mi = 0; mi < 4; mi++)
      af[mi] = *(const bf16x8*)(sA + (wr * 64 + mi * 16 + frow) * 32 + koff);
#pragma unroll
    for (int ni = 0; ni < 4; ni++)
      bfr[ni] = *(const bf16x8*)(sB + (wc * 64 + ni * 16 + frow) * 32 + koff);
#pragma unroll
    for (int mi = 0; mi < 4; mi++)
#pragma unroll
      for (int ni = 0; ni < 4; ni++)
        acc[mi][ni] = __builtin_amdgcn_mfma_f32_16x16x32_bf16(af[mi], bfr[ni], acc[mi][ni], 0, 0, 0);
    __syncthreads();
  }

#pragma unroll
  for (int mi = 0; mi < 4; mi++) {
    int grow0 = bm * 128 + wr * 64 + mi * 16 + (lane >> 4) * 4;
#pragma unroll
    for (int ni = 0; ni < 4; ni++) {
      int gcol = wc * 64 + ni * 16 + (lane & 15);
#pragma unroll
      for (int r = 0; r < 4; r++) {
        int grow = grow0 + r;
        if (grow < mreal) C[(size_t)grow * ldc + gcol] = acc[mi][ni][r];
      }
    }
  }
}

// ---------------- layer-1 fused edge softmax + aggregate + activation + hi/lo split ----------------

__global__ __launch_bounds__(256)
void edge_agg1(const unsigned short* __restrict__ XL1,
               const int* __restrict__ row_ptr, const int* __restrict__ csr_src,
               const float* __restrict__ att_s, const float* __restrict__ att_p,
               const float* __restrict__ b_s, const float* __restrict__ b_p,
               unsigned short* __restrict__ A2s, unsigned short* __restrict__ A2p) {
  int gw = (blockIdx.x * 256 + threadIdx.x) >> 6;
  if (gw >= NN * 2) return;
  int n = gw >> 1, br = gw & 1;
  int lane = threadIdx.x & 63;
  int cb = lane * 8;
  const float* att = br ? att_p : att_s;
  const float* bias = br ? b_p : b_s;
  float xr[8], at[8], agg[8];
  bf16x8 xrv = *(const bf16x8*)(XL1 + (size_t)n * NCOL1 + br * 1024 + 512 + cb);
#pragma unroll
  for (int j = 0; j < 8; j++) { xr[j] = (float)xrv[j]; at[j] = att[cb + j]; agg[j] = 0.f; }
  float M = -1e30f, S = 0.f;
  const size_t srcoff = (size_t)br * 1024 + cb;
  int pe = row_ptr[n + 1];
  for (int p = row_ptr[n]; p < pe; ++p) {
    int src = csr_src[p];
    bf16x8 mv = *(const bf16x8*)(XL1 + (size_t)src * NCOL1 + srcoff);
    float mj[8], part = 0.f;
#pragma unroll
    for (int j = 0; j < 8; j++) {
      mj[j] = (float)mv[j];
      float t = mj[j] + xr[j];
      t = (t > 0.f) ? t : 0.2f * t;
      part = fmaf(at[j], t, part);
    }
#pragma unroll
    for (int w = 1; w < 16; w <<= 1) part += __shfl_xor(part, w);
    float nm = fmaxf(M, part);
    float fac = __expf(M - nm);
    float wgt = __expf(part - nm);
    S = S * fac + wgt;
#pragma unroll
    for (int j = 0; j < 8; j++) agg[j] = agg[j] * fac + wgt * mj[j];
    M = nm;
  }
  float inv = 1.f / S;
  u16x8 hv, lv;
  unsigned short* A2 = br ? A2p : A2s;
#pragma unroll
  for (int j = 0; j < 8; j++) {
    float v = agg[j] * inv + bias[cb + j];
    if (!br) v = fmaxf(v, 0.f);
    unsigned short h = f2bf(v);
    float lo = v - bf2f(h);
    hv[j] = h; lv[j] = f2bf(lo);
  }
  *(u16x8*)(A2 + (size_t)n * LDA2 + cb) = hv;
  *(u16x8*)(A2 + (size_t)n * LDA2 + 512 + cb) = lv;
}

// ---------------- layer-2 fused edge softmax + aggregate + final epilogue ----------------

__global__ __launch_bounds__(256)
void edge_agg2(const float* __restrict__ C2s, const float* __restrict__ C2p,
               const int* __restrict__ row_ptr, const int* __restrict__ csr_src,
               const float* __restrict__ att_s, const float* __restrict__ att_p,
               const float* __restrict__ b_s, const float* __restrict__ b_p,
               float* __restrict__ out) {
  int gw = (blockIdx.x * 256 + threadIdx.x) >> 6;
  if (gw >= NN * 2) return;
  int n = gw >> 1, br = gw & 1;
  int lane = threadIdx.x & 63;
  const float* C2 = br ? C2p : C2s;
  float xr = C2[(size_t)n * 128 + 64 + lane];
  float at = (br ? att_p : att_s)[lane];
  float M = -1e30f, S = 0.f, agg = 0.f;
  int pe = row_ptr[n + 1];
  for (int p = row_ptr[n]; p < pe; ++p) {
    int src = csr_src[p];
    float m = C2[(size_t)src * 128 + lane];
    float t = m + xr;
    t = (t > 0.f) ? t : 0.2f * t;
    float part = at * t;
#pragma unroll
    for (int w = 1; w < 64; w <<= 1) part += __shfl_xor(part, w);
    float nm = fmaxf(M, part);
    float fac = __expf(M - nm);
    float wgt = __expf(part - nm);
    S = S * fac + wgt;
    agg = agg * fac + wgt * m;
    M = nm;
  }
  float v = agg / S + (br ? b_p : b_s)[lane];
  if (lane < 32) {
    out[(size_t)n * 64 + br * 32 + lane] = v;
  } else {
    float sp = fmaxf(v, 0.f) + log1pf(__expf(-fabsf(v))) + 1e-6f;
    out[(size_t)MU_SZ + n * 64 + br * 32 + (lane - 32)] = sp;
  }
}

// ---------------- host ----------------

extern "C" void kernel_launch(void* const* d_in, const int* in_sizes, int n_in,
                              void* d_out, int out_size, void* d_ws, size_t ws_size,
                              hipStream_t stream) {
  const float* x      = (const float*)d_in[0];
  const int*   ei     = (const int*)d_in[1];
  const float* Wl_s1  = (const float*)d_in[2];
  const float* Wr_s1  = (const float*)d_in[3];
  const float* att_s1 = (const float*)d_in[4];
  const float* b_s1   = (const float*)d_in[5];
  const float* Wl_s2  = (const float*)d_in[6];
  const float* Wr_s2  = (const float*)d_in[7];
  const float* att_s2 = (const float*)d_in[8];
  const float* b_s2   = (const float*)d_in[9];
  const float* Wl_p1  = (const float*)d_in[10];
  const float* Wr_p1  = (const float*)d_in[11];
  const float* att_p1 = (const float*)d_in[12];
  const float* b_p1   = (const float*)d_in[13];
  const float* Wl_p2  = (const float*)d_in[14];
  const float* Wr_p2  = (const float*)d_in[15];
  const float* att_p2 = (const float*)d_in[16];
  const float* b_p2   = (const float*)d_in[17];

  char* ws = (char*)d_ws;
  // Region R0 [0, 124.3MB): Xb during GEMM1; reused afterwards for layer-2 buffers.
  unsigned short* Xb   = (unsigned short*)(ws + 0);           // 20224*3072*2 = 124,256,256
  unsigned short* A2s  = (unsigned short*)(ws + 0);           // 41,156,608
  unsigned short* A2p  = (unsigned short*)(ws + 41156608);    // 41,156,608
  float*          C2s  = (float*)(ws + 82313216);             // 10,240,000
  float*          C2p  = (float*)(ws + 92553216);             // 10,240,000
  unsigned short* B2s  = (unsigned short*)(ws + 102793216);   // 262,144
  unsigned short* B2p  = (unsigned short*)(ws + 103055360);   // 262,144
  unsigned short* Wp   = (unsigned short*)(ws + 124256256);   // 12,582,912
  unsigned short* XL1  = (unsigned short*)(ws + 136839168);   // 20224*2048*2 = 82,837,504
  int* counts  = (int*)(ws + 219676672);
  int* fill    = (int*)(ws + 219756672);
  int* row_ptr = (int*)(ws + 219836672);
  int* csr_src = (int*)(ws + 219916688);                      // ends ~221.3 MB

  hipMemsetAsync(counts, 0, NN * sizeof(int), stream);
  hipMemsetAsync(fill, 0, NN * sizeof(int), stream);

  k_convert_x<<<30336, 256, 0, stream>>>(x, Xb);
  k_pack_w1<<<dim3(48, 32), 256, 0, stream>>>(Wl_s1, Wr_s1, Wl_p1, Wr_p1, Wp);
  k_count<<<(ETOT + 255) / 256, 256, 0, stream>>>(ei, counts);
  k_scan<<<1, 1024, 0, stream>>>(counts, row_ptr);
  k_scatter<<<(ETOT + 255) / 256, 256, 0, stream>>>(ei, row_ptr, fill, csr_src);

  // XL1[n, 0:512|512:1024|1024:1536|1536:2048] = x@{Wl_s1|Wr_s1|Wl_p1|Wr_p1}, bf16
  gemm256<<<632, 512, 0, stream>>>(Xb, Wp, XL1);

  k_pack_w2<<<512, 256, 0, stream>>>(Wl_s2, Wr_s2, B2s);
  k_pack_w2<<<512, 256, 0, stream>>>(Wl_p2, Wr_p2, B2p);

  edge_agg1<<<10000, 256, 0, stream>>>(XL1, row_ptr, csr_src, att_s1, att_p1, b_s1, b_p1, A2s, A2p);

  // layer-2: both branches, one launch
  gemm_l2<<<dim3(157, 2), 256, 0, stream>>>(A2s, B2s, C2s, A2p, B2p, C2p);

  edge_agg2<<<10000, 256, 0, stream>>>(C2s, C2p, row_ptr, csr_src, att_s2, att_p2, b_s2, b_p2, (float*)d_out);
}